// Round 4
// baseline (290.167 us; speedup 1.0000x reference)
//
#include <hip/hip_runtime.h>
#include <math.h>
#include <stdint.h>

#define T_TOK 8192
#define HDIM 1024
#define IDIM 512
#define NEXP 8
#define NGRP 2
#define EPG 4

typedef unsigned short u16;
typedef __attribute__((ext_vector_type(8))) short short8;   // 8 bf16 in 4 VGPRs
typedef __attribute__((ext_vector_type(4))) float f32x4;

// async global->LDS, 16B per lane; LDS dest is wave-uniform base (HW adds lane*16)
#define GLD16(gp, lp) __builtin_amdgcn_global_load_lds(                        \
    (const __attribute__((address_space(1))) unsigned int*)(gp),               \
    (__attribute__((address_space(3))) unsigned int*)(lp), 16, 0, 0)

__device__ __forceinline__ u16 f2bf(float f) {  // RNE float->bf16
    unsigned int u = __float_as_uint(f);
    u += 0x7fffu + ((u >> 16) & 1u);
    return (u16)(u >> 16);
}
__device__ __forceinline__ float bf2f(u16 v) {
    return __uint_as_float(((unsigned int)v) << 16);
}

// ---------------- router: one wave per token; no atomics ----------------
__global__ __launch_bounds__(256)
void router_kernel(const float* __restrict__ X,
                   const float* __restrict__ Wr,    // [E,H]
                   const float* __restrict__ bias,  // [E]
                   u16* __restrict__ Xb,            // [T,H] bf16 out
                   float* __restrict__ wpair,       // [2T]
                   int* __restrict__ topk_ids)      // [T] packed i0 | i1<<8
{
    int wave = threadIdx.x >> 6;
    int lane = threadIdx.x & 63;
    int t = blockIdx.x * 4 + wave;
    if (t >= T_TOK) return;

    float acc[NEXP];
#pragma unroll
    for (int e = 0; e < NEXP; ++e) acc[e] = 0.f;

    const float4* X4 = (const float4*)(X + (size_t)t * HDIM);
#pragma unroll
    for (int jj = 0; jj < 4; ++jj) {
        float4 xv = X4[lane + jj * 64];
        ushort4 bv;
        bv.x = f2bf(xv.x); bv.y = f2bf(xv.y); bv.z = f2bf(xv.z); bv.w = f2bf(xv.w);
        *(ushort4*)(Xb + (size_t)t * HDIM + (size_t)(lane + jj * 64) * 4) = bv;
#pragma unroll
        for (int e = 0; e < NEXP; ++e) {
            const float4* W4 = (const float4*)(Wr + (size_t)e * HDIM);
            float4 wv = W4[lane + jj * 64];
            acc[e] += xv.x * wv.x + xv.y * wv.y + xv.z * wv.z + xv.w * wv.w;
        }
    }
#pragma unroll
    for (int e = 0; e < NEXP; ++e) {
#pragma unroll
        for (int off = 32; off >= 1; off >>= 1)
            acc[e] += __shfl_xor(acc[e], off, 64);
    }

    if (lane == 0) {
        float s[NEXP], b[NEXP];
#pragma unroll
        for (int e = 0; e < NEXP; ++e) {
            s[e] = 1.f / (1.f + expf(-acc[e]));
            b[e] = s[e] + bias[e];
        }
        float gs[NGRP];
#pragma unroll
        for (int g = 0; g < NGRP; ++g) {
            float m1 = -1e30f, m2 = -1e30f;
#pragma unroll
            for (int j = 0; j < EPG; ++j) {
                float v = b[g * EPG + j];
                if (v > m1) { m2 = m1; m1 = v; }
                else if (v > m2) { m2 = v; }
            }
            gs[g] = m1 + m2;
        }
        int bg = (gs[1] > gs[0]) ? 1 : 0;
        float masked[NEXP];
#pragma unroll
        for (int e = 0; e < NEXP; ++e)
            masked[e] = ((e >> 2) == bg) ? b[e] : 0.0f;
        int i0 = 0; float v0 = masked[0];
#pragma unroll
        for (int e = 1; e < NEXP; ++e)
            if (masked[e] > v0) { v0 = masked[e]; i0 = e; }
        int i1 = -1; float v1 = -1e30f;
#pragma unroll
        for (int e = 0; e < NEXP; ++e) {
            if (e == i0) continue;
            if (masked[e] > v1) { v1 = masked[e]; i1 = e; }
        }
        float w0 = s[i0], w1 = s[i1];
        float inv = 1.f / (w0 + w1 + 1e-20f);
        w0 *= inv; w1 *= inv;
        wpair[t * 2 + 0] = w0;
        wpair[t * 2 + 1] = w1;
        topk_ids[t] = i0 | (i1 << 8);
    }
}

// ---------------- build per-expert pair lists (deterministic compaction) ----------------
__global__ __launch_bounds__(256)
void build_lists(const int* __restrict__ topk_ids,
                 int* __restrict__ counts,
                 int* __restrict__ pair_id)
{
    const int e = blockIdx.x;
    const int tid = threadIdx.x;
    const int lane = tid & 63;
    const int wid = tid >> 6;
    __shared__ int wsum[4];
    __shared__ int rb;
    if (tid == 0) rb = 0;
    __syncthreads();

    int* dst = pair_id + e * T_TOK;
    for (int c0 = 0; c0 < T_TOK; c0 += 256) {
        int t = c0 + tid;
        int ids = topk_ids[t];
        bool m0 = (ids & 0xff) == e;
        bool m1 = ((ids >> 8) & 0xff) == e;
        unsigned long long b0 = __ballot(m0);
        unsigned long long b1 = __ballot(m1);
        int n0 = __popcll(b0);
        int n1 = __popcll(b1);
        if (lane == 0) wsum[wid] = n0 + n1;
        __syncthreads();
        int pre = 0, tot = 0;
#pragma unroll
        for (int w = 0; w < 4; ++w) {
            int v = wsum[w];
            if (w < wid) pre += v;
            tot += v;
        }
        int mybase = rb + pre;
        unsigned long long ltmask = (lane == 63) ? ~0ull >> 1 : ((1ull << lane) - 1);
        if (m0) dst[mybase + __popcll(b0 & ltmask)] = t * 2;
        if (m1) dst[mybase + n0 + __popcll(b1 & ltmask)] = t * 2 + 1;
        __syncthreads();
        if (tid == 0) rb += tot;
    }
    __syncthreads();
    if (tid == 0) counts[e] = rb;
}

// ---------------- merged transpose + fp32->bf16 convert ----------------
// z<8: wg[e] (HxI), z<16: wu[e], z<24: wdn[e] (IxH), 24:swg 25:swu 26:swd
__global__ __launch_bounds__(256)
void transpose_all(const float* __restrict__ wg,  const float* __restrict__ wu,
                   const float* __restrict__ wdn, const float* __restrict__ swg,
                   const float* __restrict__ swu, const float* __restrict__ swd,
                   u16* __restrict__ wgT, u16* __restrict__ wuT, u16* __restrict__ wdnT,
                   u16* __restrict__ swgT, u16* __restrict__ swuT, u16* __restrict__ swdT)
{
    const int z = blockIdx.z;
    const float* src; u16* dst; int R, C;
    const size_t EW = (size_t)HDIM * IDIM;
    if (z < 8)       { src = wg  + (size_t)z * EW;        dst = wgT  + (size_t)z * EW;        R = HDIM; C = IDIM; }
    else if (z < 16) { src = wu  + (size_t)(z - 8) * EW;  dst = wuT  + (size_t)(z - 8) * EW;  R = HDIM; C = IDIM; }
    else if (z < 24) { src = wdn + (size_t)(z - 16) * EW; dst = wdnT + (size_t)(z - 16) * EW; R = IDIM; C = HDIM; }
    else if (z == 24){ src = swg; dst = swgT; R = HDIM; C = IDIM; }
    else if (z == 25){ src = swu; dst = swuT; R = HDIM; C = IDIM; }
    else             { src = swd; dst = swdT; R = IDIM; C = HDIM; }
    int r0 = blockIdx.x * 64, c0 = blockIdx.y * 64;
    if (r0 >= R || c0 >= C) return;

    __shared__ float tile[64][65];
    int t = threadIdx.x;
    int row = t >> 2;
#pragma unroll
    for (int j = 0; j < 4; ++j) {
        int c = ((t & 3) + j * 4) * 4;
        *(float4*)&tile[row][c] = *(const float4*)(src + (size_t)(r0 + row) * C + c0 + c);
    }
    __syncthreads();
    int c = t >> 2;
    int rchunk = (t & 3) * 16;
    __attribute__((aligned(16))) u16 pack[16];
#pragma unroll
    for (int i = 0; i < 16; ++i)
        pack[i] = f2bf(tile[rchunk + i][c]);
    uint4* d4 = (uint4*)(dst + (size_t)(c0 + c) * R + r0 + rchunk);
    d4[0] = *(uint4*)&pack[0];
    d4[1] = *(uint4*)&pack[8];
}

// ---------------- merged gate/up MFMA GEMM + SiLU -> h (bf16), 2-phase pipelined ----------------
// z=0: shared (Xb -> hs). z=1..8: expert z-1 (gathered Xb -> hp by pair id).
__global__ __launch_bounds__(256)
void gateup_all(const u16* __restrict__ Xb,
                const u16* __restrict__ WgT, const u16* __restrict__ WuT,     // [E,I,H]
                const u16* __restrict__ sWgT, const u16* __restrict__ sWuT,   // [I,H]
                u16* __restrict__ hs,   // [T,I]
                u16* __restrict__ hp,   // [2T,I]
                const int* __restrict__ counts,
                const int* __restrict__ pair_id)
{
    const int z = blockIdx.z;
    const bool SH = (z == 0);
    const int e = z - 1;
    const int nrows = SH ? T_TOK : counts[e];
    const int bm0 = blockIdx.x * 128;
    if (bm0 >= nrows) return;
    const int bn0 = blockIdx.y * 64;
    const u16* wgT = SH ? sWgT : WgT + (size_t)e * HDIM * IDIM;
    const u16* wuT = SH ? sWuT : WuT + (size_t)e * HDIM * IDIM;
    const int* plist = SH ? nullptr : (pair_id + e * T_TOK);
    u16* hout = SH ? hs : hp;

    __shared__ __attribute__((aligned(16))) short As[2 * 128 * 64];  // 32 KB
    __shared__ __attribute__((aligned(16))) short Bg[2 * 64 * 64];   // 16 KB
    __shared__ __attribute__((aligned(16))) short Bu[2 * 64 * 64];   // 16 KB

    const int tid = threadIdx.x;
    const int lane = tid & 63;
    const int wid = tid >> 6;

    const char* aptr[4];
#pragma unroll
    for (int i = 0; i < 4; ++i) {
        int r = (wid * 4 + i) * 8 + (lane >> 3);
        int row = bm0 + r;
        int srow;
        if (SH) srow = row;
        else    srow = (row < nrows) ? (plist[row] >> 1) : 0;
        int cslot = ((lane & 7) ^ (r & 7)) * 8;
        aptr[i] = (const char*)(Xb + (size_t)srow * HDIM + cslot);
    }
    const char* bgptr[2]; const char* buptr[2];
#pragma unroll
    for (int i = 0; i < 2; ++i) {
        int r = (wid * 2 + i) * 8 + (lane >> 3);
        int nn = bn0 + r;
        int cslot = ((lane & 7) ^ (r & 7)) * 8;
        bgptr[i] = (const char*)(wgT + (size_t)nn * HDIM + cslot);
        buptr[i] = (const char*)(wuT + (size_t)nn * HDIM + cslot);
    }

    auto stage = [&](int buf) {
#pragma unroll
        for (int i = 0; i < 4; ++i) {
            GLD16(aptr[i], (char*)As + buf * 16384 + (wid * 4 + i) * 1024);
            aptr[i] += 128;
        }
#pragma unroll
        for (int i = 0; i < 2; ++i) {
            GLD16(bgptr[i], (char*)Bg + buf * 8192 + (wid * 2 + i) * 1024);
            GLD16(buptr[i], (char*)Bu + buf * 8192 + (wid * 2 + i) * 1024);
            bgptr[i] += 128; buptr[i] += 128;
        }
    };

    const int wm = wid >> 1, wn = wid & 1;
    const int m0 = wm * 64, n0 = wn * 32;
    const int lr = lane & 15, lg = lane >> 4;

    f32x4 accg[4][2] = {};
    f32x4 accu[4][2] = {};

    stage(0);
    __syncthreads();
    int cur = 0;
    for (int k0 = 0; k0 < 16; ++k0) {
        if (k0 < 15) stage(cur ^ 1);   // next-tile loads fly under this tile's MFMAs
        const char* asb = (const char*)As + cur * 16384;
        const char* bgb = (const char*)Bg + cur * 8192;
        const char* bub = (const char*)Bu + cur * 8192;
#pragma unroll
        for (int kk = 0; kk < 2; ++kk) {
            short8 af[4], bgf[2], buf_[2];
#pragma unroll
            for (int mf = 0; mf < 4; ++mf) {
                int row = m0 + mf * 16 + lr;
                int slot = (kk * 4 + lg) ^ (row & 7);
                af[mf] = *(const short8*)(asb + row * 128 + slot * 16);
            }
#pragma unroll
            for (int nf = 0; nf < 2; ++nf) {
                int row = n0 + nf * 16 + lr;
                int slot = (kk * 4 + lg) ^ (row & 7);
                bgf[nf]  = *(const short8*)(bgb + row * 128 + slot * 16);
                buf_[nf] = *(const short8*)(bub + row * 128 + slot * 16);
            }
#pragma unroll
            for (int mf = 0; mf < 4; ++mf)
#pragma unroll
                for (int nf = 0; nf < 2; ++nf) {
                    accg[mf][nf] = __builtin_amdgcn_mfma_f32_16x16x32_bf16(af[mf], bgf[nf],  accg[mf][nf], 0, 0, 0);
                    accu[mf][nf] = __builtin_amdgcn_mfma_f32_16x16x32_bf16(af[mf], buf_[nf], accu[mf][nf], 0, 0, 0);
                }
        }
        __syncthreads();
        cur ^= 1;
    }

#pragma unroll
    for (int mf = 0; mf < 4; ++mf) {
#pragma unroll
        for (int j = 0; j < 4; ++j) {
            int row = bm0 + m0 + mf * 16 + lg * 4 + j;
            if (row >= nrows) continue;
            int outrow = SH ? row : plist[row];
            u16* dst = hout + (size_t)outrow * IDIM + bn0 + n0 + lr;
#pragma unroll
            for (int nf = 0; nf < 2; ++nf) {
                float g = accg[mf][nf][j], u = accu[mf][nf][j];
                float sg = g / (1.f + __expf(-g));
                dst[nf * 16] = f2bf(sg * u);
            }
        }
    }
}

// ---------------- routed down: slot0 -> out (fp32, exclusive rows), slot1 -> y1 (bf16) ----------------
__global__ __launch_bounds__(256)
void down_routed(const u16* __restrict__ Hp,      // [2T,I]
                 const u16* __restrict__ WdT,     // [E,H,I]
                 float* __restrict__ out,         // [T,H]
                 u16* __restrict__ y1,            // [T,H]
                 const float* __restrict__ wpair,
                 const int* __restrict__ counts,
                 const int* __restrict__ pair_id)
{
    const int e = blockIdx.z;
    const int nrows = counts[e];
    const int bm0 = blockIdx.x * 128;
    if (bm0 >= nrows) return;
    const int bn0 = blockIdx.y * 128;
    const u16* wdT = WdT + (size_t)e * HDIM * IDIM;
    const int* plist = pair_id + e * T_TOK;

    __shared__ __attribute__((aligned(16))) short As[2 * 128 * 64];  // 32 KB
    __shared__ __attribute__((aligned(16))) short Bs[2 * 128 * 64];  // 32 KB

    const int tid = threadIdx.x;
    const int lane = tid & 63;
    const int wid = tid >> 6;

    const char* aptr[4];
#pragma unroll
    for (int i = 0; i < 4; ++i) {
        int r = (wid * 4 + i) * 8 + (lane >> 3);
        int row = bm0 + r;
        int srow = (row < nrows) ? plist[row] : 0;
        int cslot = ((lane & 7) ^ (r & 7)) * 8;
        aptr[i] = (const char*)(Hp + (size_t)srow * IDIM + cslot);
    }
    const char* bptr[4];
#pragma unroll
    for (int i = 0; i < 4; ++i) {
        int r = (wid * 4 + i) * 8 + (lane >> 3);
        int nn = bn0 + r;
        int cslot = ((lane & 7) ^ (r & 7)) * 8;
        bptr[i] = (const char*)(wdT + (size_t)nn * IDIM + cslot);
    }

    auto stage = [&](int buf) {
#pragma unroll
        for (int i = 0; i < 4; ++i) {
            GLD16(aptr[i], (char*)As + buf * 16384 + (wid * 4 + i) * 1024);
            GLD16(bptr[i], (char*)Bs + buf * 16384 + (wid * 4 + i) * 1024);
            aptr[i] += 128; bptr[i] += 128;
        }
    };

    const int wm = wid >> 1, wn = wid & 1;
    const int m0 = wm * 64, n0 = wn * 64;
    const int lr = lane & 15, lg = lane >> 4;

    f32x4 acc[4][4] = {};

    stage(0);
    __syncthreads();
    int cur = 0;
    for (int k0 = 0; k0 < 8; ++k0) {
        if (k0 < 7) stage(cur ^ 1);
        const char* asb = (const char*)As + cur * 16384;
        const char* bsb = (const char*)Bs + cur * 16384;
#pragma unroll
        for (int kk = 0; kk < 2; ++kk) {
            short8 af[4], bf[4];
#pragma unroll
            for (int mf = 0; mf < 4; ++mf) {
                int row = m0 + mf * 16 + lr;
                int slot = (kk * 4 + lg) ^ (row & 7);
                af[mf] = *(const short8*)(asb + row * 128 + slot * 16);
            }
#pragma unroll
            for (int nf = 0; nf < 4; ++nf) {
                int row = n0 + nf * 16 + lr;
                int slot = (kk * 4 + lg) ^ (row & 7);
                bf[nf] = *(const short8*)(bsb + row * 128 + slot * 16);
            }
#pragma unroll
            for (int mf = 0; mf < 4; ++mf)
#pragma unroll
                for (int nf = 0; nf < 4; ++nf)
                    acc[mf][nf] = __builtin_amdgcn_mfma_f32_16x16x32_bf16(af[mf], bf[nf], acc[mf][nf], 0, 0, 0);
        }
        __syncthreads();
        cur ^= 1;
    }

#pragma unroll
    for (int mf = 0; mf < 4; ++mf) {
#pragma unroll
        for (int j = 0; j < 4; ++j) {
            int row = bm0 + m0 + mf * 16 + lg * 4 + j;
            if (row >= nrows) continue;
            int p = plist[row];
            int t = p >> 1;
            float w = wpair[p];
            if ((p & 1) == 0) {
                float* dst = out + (size_t)t * HDIM + bn0 + n0 + lr;
#pragma unroll
                for (int nf = 0; nf < 4; ++nf)
                    dst[nf * 16] = acc[mf][nf][j] * w;
            } else {
                u16* dst = y1 + (size_t)t * HDIM + bn0 + n0 + lr;
#pragma unroll
                for (int nf = 0; nf < 4; ++nf)
                    dst[nf * 16] = f2bf(acc[mf][nf][j] * w);
            }
        }
    }
}

// ---------------- shared down + combine: out = out(slot0) + y1(slot1) + hs@swd ----------------
__global__ __launch_bounds__(256)
void down_shared_combine(const u16* __restrict__ Hs,   // [T,I]
                         const u16* __restrict__ swdT, // [H,I]
                         const u16* __restrict__ y1,   // [T,H]
                         float* __restrict__ out)      // [T,H]
{
    const int bm0 = blockIdx.x * 128;
    const int bn0 = blockIdx.y * 128;

    __shared__ __attribute__((aligned(16))) short As[2 * 128 * 64];
    __shared__ __attribute__((aligned(16))) short Bs[2 * 128 * 64];

    const int tid = threadIdx.x;
    const int lane = tid & 63;
    const int wid = tid >> 6;

    const char* aptr[4];
#pragma unroll
    for (int i = 0; i < 4; ++i) {
        int r = (wid * 4 + i) * 8 + (lane >> 3);
        int cslot = ((lane & 7) ^ (r & 7)) * 8;
        aptr[i] = (const char*)(Hs + (size_t)(bm0 + r) * IDIM + cslot);
    }
    const char* bptr[4];
#pragma unroll
    for (int i = 0; i < 4; ++i) {
        int r = (wid * 4 + i) * 8 + (lane >> 3);
        int cslot = ((lane & 7) ^ (r & 7)) * 8;
        bptr[i] = (const char*)(swdT + (size_t)(bn0 + r) * IDIM + cslot);
    }

    auto stage = [&](int buf) {
#pragma unroll
        for (int i = 0; i < 4; ++i) {
            GLD16(aptr[i], (char*)As + buf * 16384 + (wid * 4 + i) * 1024);
            GLD16(bptr[i], (char*)Bs + buf * 16384 + (wid * 4 + i) * 1024);
            aptr[i] += 128; bptr[i] += 128;
        }
    };

    const int wm = wid >> 1, wn = wid & 1;
    const int m0 = wm * 64, n0 = wn * 64;
    const int lr = lane & 15, lg = lane >> 4;

    f32x4 acc[4][4] = {};

    stage(0);
    __syncthreads();
    int cur = 0;
    for (int k0 = 0; k0 < 8; ++k0) {
        if (k0 < 7) stage(cur ^ 1);
        const char* asb = (const char*)As + cur * 16384;
        const char* bsb = (const char*)Bs + cur * 16384;
#pragma unroll
        for (int kk = 0; kk < 2; ++kk) {
            short8 af[4], bf[4];
#pragma unroll
            for (int mf = 0; mf < 4; ++mf) {
                int row = m0 + mf * 16 + lr;
                int slot = (kk * 4 + lg) ^ (row & 7);
                af[mf] = *(const short8*)(asb + row * 128 + slot * 16);
            }
#pragma unroll
            for (int nf = 0; nf < 4; ++nf) {
                int row = n0 + nf * 16 + lr;
                int slot = (kk * 4 + lg) ^ (row & 7);
                bf[nf] = *(const short8*)(bsb + row * 128 + slot * 16);
            }
#pragma unroll
            for (int mf = 0; mf < 4; ++mf)
#pragma unroll
                for (int nf = 0; nf < 4; ++nf)
                    acc[mf][nf] = __builtin_amdgcn_mfma_f32_16x16x32_bf16(af[mf], bf[nf], acc[mf][nf], 0, 0, 0);
        }
        __syncthreads();
        cur ^= 1;
    }

#pragma unroll
    for (int mf = 0; mf < 4; ++mf) {
#pragma unroll
        for (int j = 0; j < 4; ++j) {
            int t = bm0 + m0 + mf * 16 + lg * 4 + j;
            float* dst = out + (size_t)t * HDIM + bn0 + n0 + lr;
            const u16* ysrc = y1 + (size_t)t * HDIM + bn0 + n0 + lr;
#pragma unroll
            for (int nf = 0; nf < 4; ++nf) {
                float prev = dst[nf * 16];                  // slot0 contribution
                float yv = bf2f(ysrc[nf * 16]);             // slot1 contribution
                dst[nf * 16] = prev + yv + acc[mf][nf][j];
            }
        }
    }
}

extern "C" void kernel_launch(void* const* d_in, const int* in_sizes, int n_in,
                              void* d_out, int out_size, void* d_ws, size_t ws_size,
                              hipStream_t stream) {
    const float* X    = (const float*)d_in[0];
    const float* Wr   = (const float*)d_in[1];
    const float* bias = (const float*)d_in[2];
    const float* wg   = (const float*)d_in[3];
    const float* wu   = (const float*)d_in[4];
    const float* wdn  = (const float*)d_in[5];
    const float* swg  = (const float*)d_in[6];
    const float* swu  = (const float*)d_in[7];
    const float* swd  = (const float*)d_in[8];
    float* out = (float*)d_out;
    (void)in_sizes; (void)n_in; (void)out_size; (void)ws_size;

    char* ws = (char*)d_ws;
    const size_t MB = 1048576;
    int*   counts   = (int*)ws;                          // 32 B
    float* wpair    = (float*)(ws + 4096);               // 64 KB
    int*   pair_id  = (int*)(ws + 4096 + 65536);         // 256 KB
    int*   topk_ids = (int*)(ws + 524288);               // 32 KB
    u16* Xb   = (u16*)(ws + 1 * MB);                     // 16 MB [T,H]; reused as y1 after gateup
    u16* wgT  = (u16*)(ws + 17 * MB);                    // 8 MB [E,I,H]
    u16* wuT  = (u16*)(ws + 25 * MB);                    // 8 MB
    u16* wdnT = (u16*)(ws + 33 * MB);                    // 8 MB [E,H,I]
    u16* swgT = (u16*)(ws + 41 * MB);                    // 1 MB [I,H]
    u16* swuT = (u16*)(ws + 42 * MB);                    // 1 MB
    u16* swdT = (u16*)(ws + 43 * MB);                    // 1 MB [H,I]
    u16* hs   = (u16*)(ws + 44 * MB);                    // 8 MB [T,I]
    u16* hp   = (u16*)(ws + 52 * MB);                    // 16 MB [2T,I]
    u16* y1   = Xb;                                      // alias: Xb dead after gateup_all

    router_kernel<<<T_TOK / 4, 256, 0, stream>>>(X, Wr, bias, Xb, wpair, topk_ids);
    build_lists<<<NEXP, 256, 0, stream>>>(topk_ids, counts, pair_id);
    transpose_all<<<dim3(16, 16, 27), 256, 0, stream>>>(
        wg, wu, wdn, swg, swu, swd, wgT, wuT, wdnT, swgT, swuT, swdT);

    // one merged gateup launch: z=0 shared -> hs, z=1..8 routed -> hp
    gateup_all<<<dim3(T_TOK / 128, IDIM / 64, NEXP + 1), 256, 0, stream>>>(
        Xb, wgT, wuT, swgT, swuT, hs, hp, counts, pair_id);

    // routed down: slot0 pairs write out directly (exclusive rows), slot1 -> y1
    down_routed<<<dim3(T_TOK / 128, HDIM / 128, NEXP), 256, 0, stream>>>(
        hp, wdnT, out, y1, wpair, counts, pair_id);

    // shared down fused with combine
    down_shared_combine<<<dim3(T_TOK / 128, HDIM / 128, 1), 256, 0, stream>>>(
        hs, swdT, y1, out);
}

// Round 5
// 281.891 us; speedup vs baseline: 1.0294x; 1.0294x over previous
//
#include <hip/hip_runtime.h>
#include <math.h>
#include <stdint.h>

#define T_TOK 8192
#define HDIM 1024
#define IDIM 512
#define NEXP 8
#define NGRP 2
#define EPG 4

typedef unsigned short u16;
typedef __attribute__((ext_vector_type(8))) short short8;   // 8 bf16 in 4 VGPRs
typedef __attribute__((ext_vector_type(4))) float f32x4;

// async global->LDS, 16B per lane; LDS dest is wave-uniform base (HW adds lane*16)
#define GLD16(gp, lp) __builtin_amdgcn_global_load_lds(                        \
    (const __attribute__((address_space(1))) unsigned int*)(gp),               \
    (__attribute__((address_space(3))) unsigned int*)(lp), 16, 0, 0)

#define SBAR() __builtin_amdgcn_s_barrier()
#define SCHEDB() __builtin_amdgcn_sched_barrier(0)

__device__ __forceinline__ u16 f2bf(float f) {  // RNE float->bf16
    unsigned int u = __float_as_uint(f);
    u += 0x7fffu + ((u >> 16) & 1u);
    return (u16)(u >> 16);
}
__device__ __forceinline__ float bf2f(u16 v) {
    return __uint_as_float(((unsigned int)v) << 16);
}

// counted-vmcnt ladder: 4 loads/wave/tile, depth-4 pipeline
__device__ __forceinline__ void wait_ladder(int k, int NT) {
    if (k + 3 < NT)      asm volatile("s_waitcnt vmcnt(12)" ::: "memory");
    else if (k + 2 < NT) asm volatile("s_waitcnt vmcnt(8)"  ::: "memory");
    else if (k + 1 < NT) asm volatile("s_waitcnt vmcnt(4)"  ::: "memory");
    else                 asm volatile("s_waitcnt vmcnt(0)"  ::: "memory");
}

// ---------------- router: one wave per token; no atomics ----------------
__global__ __launch_bounds__(256)
void router_kernel(const float* __restrict__ X,
                   const float* __restrict__ Wr,    // [E,H]
                   const float* __restrict__ bias,  // [E]
                   u16* __restrict__ Xb,            // [T,H] bf16 out
                   float* __restrict__ wpair,       // [2T]
                   int* __restrict__ topk_ids)      // [T] packed i0 | i1<<8
{
    int wave = threadIdx.x >> 6;
    int lane = threadIdx.x & 63;
    int t = blockIdx.x * 4 + wave;
    if (t >= T_TOK) return;

    float acc[NEXP];
#pragma unroll
    for (int e = 0; e < NEXP; ++e) acc[e] = 0.f;

    const float4* X4 = (const float4*)(X + (size_t)t * HDIM);
#pragma unroll
    for (int jj = 0; jj < 4; ++jj) {
        float4 xv = X4[lane + jj * 64];
        ushort4 bv;
        bv.x = f2bf(xv.x); bv.y = f2bf(xv.y); bv.z = f2bf(xv.z); bv.w = f2bf(xv.w);
        *(ushort4*)(Xb + (size_t)t * HDIM + (size_t)(lane + jj * 64) * 4) = bv;
#pragma unroll
        for (int e = 0; e < NEXP; ++e) {
            const float4* W4 = (const float4*)(Wr + (size_t)e * HDIM);
            float4 wv = W4[lane + jj * 64];
            acc[e] += xv.x * wv.x + xv.y * wv.y + xv.z * wv.z + xv.w * wv.w;
        }
    }
#pragma unroll
    for (int e = 0; e < NEXP; ++e) {
#pragma unroll
        for (int off = 32; off >= 1; off >>= 1)
            acc[e] += __shfl_xor(acc[e], off, 64);
    }

    if (lane == 0) {
        float s[NEXP], b[NEXP];
#pragma unroll
        for (int e = 0; e < NEXP; ++e) {
            s[e] = 1.f / (1.f + expf(-acc[e]));
            b[e] = s[e] + bias[e];
        }
        float gs[NGRP];
#pragma unroll
        for (int g = 0; g < NGRP; ++g) {
            float m1 = -1e30f, m2 = -1e30f;
#pragma unroll
            for (int j = 0; j < EPG; ++j) {
                float v = b[g * EPG + j];
                if (v > m1) { m2 = m1; m1 = v; }
                else if (v > m2) { m2 = v; }
            }
            gs[g] = m1 + m2;
        }
        int bg = (gs[1] > gs[0]) ? 1 : 0;
        float masked[NEXP];
#pragma unroll
        for (int e = 0; e < NEXP; ++e)
            masked[e] = ((e >> 2) == bg) ? b[e] : 0.0f;
        int i0 = 0; float v0 = masked[0];
#pragma unroll
        for (int e = 1; e < NEXP; ++e)
            if (masked[e] > v0) { v0 = masked[e]; i0 = e; }
        int i1 = -1; float v1 = -1e30f;
#pragma unroll
        for (int e = 0; e < NEXP; ++e) {
            if (e == i0) continue;
            if (masked[e] > v1) { v1 = masked[e]; i1 = e; }
        }
        float w0 = s[i0], w1 = s[i1];
        float inv = 1.f / (w0 + w1 + 1e-20f);
        w0 *= inv; w1 *= inv;
        wpair[t * 2 + 0] = w0;
        wpair[t * 2 + 1] = w1;
        topk_ids[t] = i0 | (i1 << 8);
    }
}

// ---------------- build per-expert pair lists (deterministic compaction) ----------------
__global__ __launch_bounds__(256)
void build_lists(const int* __restrict__ topk_ids,
                 int* __restrict__ counts,
                 int* __restrict__ pair_id)
{
    const int e = blockIdx.x;
    const int tid = threadIdx.x;
    const int lane = tid & 63;
    const int wid = tid >> 6;
    __shared__ int wsum[4];
    __shared__ int rb;
    if (tid == 0) rb = 0;
    __syncthreads();

    int* dst = pair_id + e * T_TOK;
    for (int c0 = 0; c0 < T_TOK; c0 += 256) {
        int t = c0 + tid;
        int ids = topk_ids[t];
        bool m0 = (ids & 0xff) == e;
        bool m1 = ((ids >> 8) & 0xff) == e;
        unsigned long long b0 = __ballot(m0);
        unsigned long long b1 = __ballot(m1);
        int n0 = __popcll(b0);
        int n1 = __popcll(b1);
        if (lane == 0) wsum[wid] = n0 + n1;
        __syncthreads();
        int pre = 0, tot = 0;
#pragma unroll
        for (int w = 0; w < 4; ++w) {
            int v = wsum[w];
            if (w < wid) pre += v;
            tot += v;
        }
        int mybase = rb + pre;
        unsigned long long ltmask = (lane == 63) ? ~0ull >> 1 : ((1ull << lane) - 1);
        if (m0) dst[mybase + __popcll(b0 & ltmask)] = t * 2;
        if (m1) dst[mybase + n0 + __popcll(b1 & ltmask)] = t * 2 + 1;
        __syncthreads();
        if (tid == 0) rb += tot;
    }
    __syncthreads();
    if (tid == 0) counts[e] = rb;
}

// ---------------- merged transpose + fp32->bf16 convert ----------------
__global__ __launch_bounds__(256)
void transpose_all(const float* __restrict__ wg,  const float* __restrict__ wu,
                   const float* __restrict__ wdn, const float* __restrict__ swg,
                   const float* __restrict__ swu, const float* __restrict__ swd,
                   u16* __restrict__ wgT, u16* __restrict__ wuT, u16* __restrict__ wdnT,
                   u16* __restrict__ swgT, u16* __restrict__ swuT, u16* __restrict__ swdT)
{
    const int z = blockIdx.z;
    const float* src; u16* dst; int R, C;
    const size_t EW = (size_t)HDIM * IDIM;
    if (z < 8)       { src = wg  + (size_t)z * EW;        dst = wgT  + (size_t)z * EW;        R = HDIM; C = IDIM; }
    else if (z < 16) { src = wu  + (size_t)(z - 8) * EW;  dst = wuT  + (size_t)(z - 8) * EW;  R = HDIM; C = IDIM; }
    else if (z < 24) { src = wdn + (size_t)(z - 16) * EW; dst = wdnT + (size_t)(z - 16) * EW; R = IDIM; C = HDIM; }
    else if (z == 24){ src = swg; dst = swgT; R = HDIM; C = IDIM; }
    else if (z == 25){ src = swu; dst = swuT; R = HDIM; C = IDIM; }
    else             { src = swd; dst = swdT; R = IDIM; C = HDIM; }
    int r0 = blockIdx.x * 64, c0 = blockIdx.y * 64;
    if (r0 >= R || c0 >= C) return;

    __shared__ float tile[64][65];
    int t = threadIdx.x;
    int row = t >> 2;
#pragma unroll
    for (int j = 0; j < 4; ++j) {
        int c = ((t & 3) + j * 4) * 4;
        *(float4*)&tile[row][c] = *(const float4*)(src + (size_t)(r0 + row) * C + c0 + c);
    }
    __syncthreads();
    int c = t >> 2;
    int rchunk = (t & 3) * 16;
    __attribute__((aligned(16))) u16 pack[16];
#pragma unroll
    for (int i = 0; i < 16; ++i)
        pack[i] = f2bf(tile[rchunk + i][c]);
    uint4* d4 = (uint4*)(dst + (size_t)(c0 + c) * R + r0 + rchunk);
    d4[0] = *(uint4*)&pack[0];
    d4[1] = *(uint4*)&pack[8];
}

// ---------------- merged gate/up MFMA GEMM + SiLU -> h, BK=32 depth-4 pipeline ----------------
// z=0: shared (Xb -> hs). z=1..8: expert z-1 (gathered Xb -> hp by pair id).
// Tile 128x64(x2 matrices). 4 waves, each 64x32 per matrix. Linear LDS (conflict-free at BK=32).
__global__ __launch_bounds__(256)
void gateup_all(const u16* __restrict__ Xb,
                const u16* __restrict__ WgT, const u16* __restrict__ WuT,     // [E,I,H]
                const u16* __restrict__ sWgT, const u16* __restrict__ sWuT,   // [I,H]
                u16* __restrict__ hs,   // [T,I]
                u16* __restrict__ hp,   // [2T,I]
                const int* __restrict__ counts,
                const int* __restrict__ pair_id)
{
    const int z = blockIdx.z;
    const bool SH = (z == 0);
    const int e = z - 1;
    const int nrows = SH ? T_TOK : counts[e];
    const int bm0 = blockIdx.x * 128;
    if (bm0 >= nrows) return;
    const int bn0 = blockIdx.y * 64;
    const u16* wgT = SH ? sWgT : WgT + (size_t)e * HDIM * IDIM;
    const u16* wuT = SH ? sWuT : WuT + (size_t)e * HDIM * IDIM;
    const int* plist = SH ? nullptr : (pair_id + e * T_TOK);
    u16* hout = SH ? hs : hp;

    // 4 buffers: A 8KB, Bg 4KB, Bu 4KB each -> 64 KB total
    __shared__ __attribute__((aligned(16))) char As[4 * 8192];
    __shared__ __attribute__((aligned(16))) char Bgs[4 * 4096];
    __shared__ __attribute__((aligned(16))) char Bus[4 * 4096];

    const int tid = threadIdx.x;
    const int lane = tid & 63;
    const int wid = tid >> 6;

    // A: 8 wave-insts (16 rows each); wave does insts wid*2, wid*2+1
    const char* aptr[2];
#pragma unroll
    for (int i = 0; i < 2; ++i) {
        int g = wid * 2 + i;
        int r = g * 16 + (lane >> 2);           // tile-local row
        int row = bm0 + r;
        int srow;
        if (SH) srow = row;
        else    srow = (row < nrows) ? (plist[row] >> 1) : 0;
        aptr[i] = (const char*)(Xb + (size_t)srow * HDIM + (lane & 3) * 8);
    }
    // B: 4 wave-insts each (16 rows); wave does inst wid
    const char* bgptr; const char* buptr;
    {
        int r = wid * 16 + (lane >> 2);
        int nn = bn0 + r;
        bgptr = (const char*)(wgT + (size_t)nn * HDIM + (lane & 3) * 8);
        buptr = (const char*)(wuT + (size_t)nn * HDIM + (lane & 3) * 8);
    }

    auto stage = [&](int sl, int kt) {
        size_t koff = (size_t)kt * 64;          // 32 bf16 = 64 bytes per tile step
#pragma unroll
        for (int i = 0; i < 2; ++i)
            GLD16(aptr[i] + koff, As + sl * 8192 + (wid * 2 + i) * 1024);
        GLD16(bgptr + koff, Bgs + sl * 4096 + wid * 1024);
        GLD16(buptr + koff, Bus + sl * 4096 + wid * 1024);
    };

    const int wm = wid >> 1, wn = wid & 1;
    const int m0 = wm * 64, n0 = wn * 32;
    const int lr = lane & 15, lg = lane >> 4;

    f32x4 accg[4][2] = {};
    f32x4 accu[4][2] = {};

    const int NT = HDIM / 32;   // 32
    stage(0, 0); stage(1, 1); stage(2, 2);
    for (int k = 0; k < NT; ++k) {
        if (k + 3 < NT) stage((k + 3) & 3, k + 3);
        wait_ladder(k, NT);
        SBAR(); SCHEDB();
        const char* ab = As  + (k & 3) * 8192;
        const char* gb = Bgs + (k & 3) * 4096;
        const char* ub = Bus + (k & 3) * 4096;
        short8 af[4], bgf[2], buf_[2];
#pragma unroll
        for (int mf = 0; mf < 4; ++mf)
            af[mf] = *(const short8*)(ab + (m0 + mf * 16 + lr) * 64 + lg * 16);
#pragma unroll
        for (int nf = 0; nf < 2; ++nf) {
            bgf[nf]  = *(const short8*)(gb + (n0 + nf * 16 + lr) * 64 + lg * 16);
            buf_[nf] = *(const short8*)(ub + (n0 + nf * 16 + lr) * 64 + lg * 16);
        }
#pragma unroll
        for (int mf = 0; mf < 4; ++mf)
#pragma unroll
            for (int nf = 0; nf < 2; ++nf) {
                accg[mf][nf] = __builtin_amdgcn_mfma_f32_16x16x32_bf16(af[mf], bgf[nf],  accg[mf][nf], 0, 0, 0);
                accu[mf][nf] = __builtin_amdgcn_mfma_f32_16x16x32_bf16(af[mf], buf_[nf], accu[mf][nf], 0, 0, 0);
            }
        SBAR(); SCHEDB();
    }

    // epilogue: C/D layout col=lane&15, row=4*(lane>>4)+reg
#pragma unroll
    for (int mf = 0; mf < 4; ++mf) {
#pragma unroll
        for (int j = 0; j < 4; ++j) {
            int row = bm0 + m0 + mf * 16 + lg * 4 + j;
            if (row >= nrows) continue;
            int outrow = SH ? row : plist[row];
            u16* dst = hout + (size_t)outrow * IDIM + bn0 + n0 + lr;
#pragma unroll
            for (int nf = 0; nf < 2; ++nf) {
                float g = accg[mf][nf][j], u = accu[mf][nf][j];
                float sg = g / (1.f + __expf(-g));
                dst[nf * 16] = f2bf(sg * u);
            }
        }
    }
}

// ---------------- routed down: slot0 -> out (fp32, exclusive rows), slot1 -> y1 (bf16) ----------------
// Tile 128x128, BK=32, depth-4. 4 waves, each 64x64.
__global__ __launch_bounds__(256)
void down_routed(const u16* __restrict__ Hp,      // [2T,I]
                 const u16* __restrict__ WdT,     // [E,H,I]
                 float* __restrict__ out,         // [T,H]
                 u16* __restrict__ y1,            // [T,H]
                 const float* __restrict__ wpair,
                 const int* __restrict__ counts,
                 const int* __restrict__ pair_id)
{
    const int e = blockIdx.z;
    const int nrows = counts[e];
    const int bm0 = blockIdx.x * 128;
    if (bm0 >= nrows) return;
    const int bn0 = blockIdx.y * 128;
    const u16* wdT = WdT + (size_t)e * HDIM * IDIM;
    const int* plist = pair_id + e * T_TOK;

    __shared__ __attribute__((aligned(16))) char As[4 * 8192];
    __shared__ __attribute__((aligned(16))) char Bs[4 * 8192];

    const int tid = threadIdx.x;
    const int lane = tid & 63;
    const int wid = tid >> 6;

    const char* aptr[2];
#pragma unroll
    for (int i = 0; i < 2; ++i) {
        int g = wid * 2 + i;
        int r = g * 16 + (lane >> 2);
        int row = bm0 + r;
        int srow = (row < nrows) ? plist[row] : 0;
        aptr[i] = (const char*)(Hp + (size_t)srow * IDIM + (lane & 3) * 8);
    }
    const char* bptr[2];
#pragma unroll
    for (int i = 0; i < 2; ++i) {
        int g = wid * 2 + i;
        int r = g * 16 + (lane >> 2);
        bptr[i] = (const char*)(wdT + (size_t)(bn0 + r) * IDIM + (lane & 3) * 8);
    }

    auto stage = [&](int sl, int kt) {
        size_t koff = (size_t)kt * 64;
#pragma unroll
        for (int i = 0; i < 2; ++i) {
            GLD16(aptr[i] + koff, As + sl * 8192 + (wid * 2 + i) * 1024);
            GLD16(bptr[i] + koff, Bs + sl * 8192 + (wid * 2 + i) * 1024);
        }
    };

    const int wm = wid >> 1, wn = wid & 1;
    const int m0 = wm * 64, n0 = wn * 64;
    const int lr = lane & 15, lg = lane >> 4;

    f32x4 acc[4][4] = {};

    const int NT = IDIM / 32;   // 16
    stage(0, 0); stage(1, 1); stage(2, 2);
    for (int k = 0; k < NT; ++k) {
        if (k + 3 < NT) stage((k + 3) & 3, k + 3);
        wait_ladder(k, NT);
        SBAR(); SCHEDB();
        const char* ab = As + (k & 3) * 8192;
        const char* bb = Bs + (k & 3) * 8192;
        short8 af[4], bf[4];
#pragma unroll
        for (int mf = 0; mf < 4; ++mf)
            af[mf] = *(const short8*)(ab + (m0 + mf * 16 + lr) * 64 + lg * 16);
#pragma unroll
        for (int nf = 0; nf < 4; ++nf)
            bf[nf] = *(const short8*)(bb + (n0 + nf * 16 + lr) * 64 + lg * 16);
#pragma unroll
        for (int mf = 0; mf < 4; ++mf)
#pragma unroll
            for (int nf = 0; nf < 4; ++nf)
                acc[mf][nf] = __builtin_amdgcn_mfma_f32_16x16x32_bf16(af[mf], bf[nf], acc[mf][nf], 0, 0, 0);
        SBAR(); SCHEDB();
    }

#pragma unroll
    for (int mf = 0; mf < 4; ++mf) {
#pragma unroll
        for (int j = 0; j < 4; ++j) {
            int row = bm0 + m0 + mf * 16 + lg * 4 + j;
            if (row >= nrows) continue;
            int p = plist[row];
            int t = p >> 1;
            float w = wpair[p];
            if ((p & 1) == 0) {
                float* dst = out + (size_t)t * HDIM + bn0 + n0 + lr;
#pragma unroll
                for (int nf = 0; nf < 4; ++nf)
                    dst[nf * 16] = acc[mf][nf][j] * w;
            } else {
                u16* dst = y1 + (size_t)t * HDIM + bn0 + n0 + lr;
#pragma unroll
                for (int nf = 0; nf < 4; ++nf)
                    dst[nf * 16] = f2bf(acc[mf][nf][j] * w);
            }
        }
    }
}

// ---------------- shared down + combine: out = out(slot0) + y1(slot1) + hs@swd ----------------
__global__ __launch_bounds__(256)
void down_shared_combine(const u16* __restrict__ Hs,   // [T,I]
                         const u16* __restrict__ swdT, // [H,I]
                         const u16* __restrict__ y1,   // [T,H]
                         float* __restrict__ out)      // [T,H]
{
    const int bm0 = blockIdx.x * 128;
    const int bn0 = blockIdx.y * 128;

    __shared__ __attribute__((aligned(16))) char As[4 * 8192];
    __shared__ __attribute__((aligned(16))) char Bs[4 * 8192];

    const int tid = threadIdx.x;
    const int lane = tid & 63;
    const int wid = tid >> 6;

    const char* aptr[2];
#pragma unroll
    for (int i = 0; i < 2; ++i) {
        int g = wid * 2 + i;
        int r = g * 16 + (lane >> 2);
        aptr[i] = (const char*)(Hs + (size_t)(bm0 + r) * IDIM + (lane & 3) * 8);
    }
    const char* bptr[2];
#pragma unroll
    for (int i = 0; i < 2; ++i) {
        int g = wid * 2 + i;
        int r = g * 16 + (lane >> 2);
        bptr[i] = (const char*)(swdT + (size_t)(bn0 + r) * IDIM + (lane & 3) * 8);
    }

    auto stage = [&](int sl, int kt) {
        size_t koff = (size_t)kt * 64;
#pragma unroll
        for (int i = 0; i < 2; ++i) {
            GLD16(aptr[i] + koff, As + sl * 8192 + (wid * 2 + i) * 1024);
            GLD16(bptr[i] + koff, Bs + sl * 8192 + (wid * 2 + i) * 1024);
        }
    };

    const int wm = wid >> 1, wn = wid & 1;
    const int m0 = wm * 64, n0 = wn * 64;
    const int lr = lane & 15, lg = lane >> 4;

    f32x4 acc[4][4] = {};

    const int NT = IDIM / 32;   // 16
    stage(0, 0); stage(1, 1); stage(2, 2);
    for (int k = 0; k < NT; ++k) {
        if (k + 3 < NT) stage((k + 3) & 3, k + 3);
        wait_ladder(k, NT);
        SBAR(); SCHEDB();
        const char* ab = As + (k & 3) * 8192;
        const char* bb = Bs + (k & 3) * 8192;
        short8 af[4], bf[4];
#pragma unroll
        for (int mf = 0; mf < 4; ++mf)
            af[mf] = *(const short8*)(ab + (m0 + mf * 16 + lr) * 64 + lg * 16);
#pragma unroll
        for (int nf = 0; nf < 4; ++nf)
            bf[nf] = *(const short8*)(bb + (n0 + nf * 16 + lr) * 64 + lg * 16);
#pragma unroll
        for (int mf = 0; mf < 4; ++mf)
#pragma unroll
            for (int nf = 0; nf < 4; ++nf)
                acc[mf][nf] = __builtin_amdgcn_mfma_f32_16x16x32_bf16(af[mf], bf[nf], acc[mf][nf], 0, 0, 0);
        SBAR(); SCHEDB();
    }

#pragma unroll
    for (int mf = 0; mf < 4; ++mf) {
#pragma unroll
        for (int j = 0; j < 4; ++j) {
            int t = bm0 + m0 + mf * 16 + lg * 4 + j;
            float* dst = out + (size_t)t * HDIM + bn0 + n0 + lr;
            const u16* ysrc = y1 + (size_t)t * HDIM + bn0 + n0 + lr;
#pragma unroll
            for (int nf = 0; nf < 4; ++nf) {
                float prev = dst[nf * 16];                  // slot0 contribution
                float yv = bf2f(ysrc[nf * 16]);             // slot1 contribution
                dst[nf * 16] = prev + yv + acc[mf][nf][j];
            }
        }
    }
}

extern "C" void kernel_launch(void* const* d_in, const int* in_sizes, int n_in,
                              void* d_out, int out_size, void* d_ws, size_t ws_size,
                              hipStream_t stream) {
    const float* X    = (const float*)d_in[0];
    const float* Wr   = (const float*)d_in[1];
    const float* bias = (const float*)d_in[2];
    const float* wg   = (const float*)d_in[3];
    const float* wu   = (const float*)d_in[4];
    const float* wdn  = (const float*)d_in[5];
    const float* swg  = (const float*)d_in[6];
    const float* swu  = (const float*)d_in[7];
    const float* swd  = (const float*)d_in[8];
    float* out = (float*)d_out;
    (void)in_sizes; (void)n_in; (void)out_size; (void)ws_size;

    char* ws = (char*)d_ws;
    const size_t MB = 1048576;
    int*   counts   = (int*)ws;                          // 32 B
    float* wpair    = (float*)(ws + 4096);               // 64 KB
    int*   pair_id  = (int*)(ws + 4096 + 65536);         // 256 KB
    int*   topk_ids = (int*)(ws + 524288);               // 32 KB
    u16* Xb   = (u16*)(ws + 1 * MB);                     // 16 MB [T,H]; reused as y1 after gateup
    u16* wgT  = (u16*)(ws + 17 * MB);                    // 8 MB [E,I,H]
    u16* wuT  = (u16*)(ws + 25 * MB);                    // 8 MB
    u16* wdnT = (u16*)(ws + 33 * MB);                    // 8 MB [E,H,I]
    u16* swgT = (u16*)(ws + 41 * MB);                    // 1 MB [I,H]
    u16* swuT = (u16*)(ws + 42 * MB);                    // 1 MB
    u16* swdT = (u16*)(ws + 43 * MB);                    // 1 MB [H,I]
    u16* hs   = (u16*)(ws + 44 * MB);                    // 8 MB [T,I]
    u16* hp   = (u16*)(ws + 52 * MB);                    // 16 MB [2T,I]
    u16* y1   = Xb;                                      // alias: Xb dead after gateup_all

    router_kernel<<<T_TOK / 4, 256, 0, stream>>>(X, Wr, bias, Xb, wpair, topk_ids);
    build_lists<<<NEXP, 256, 0, stream>>>(topk_ids, counts, pair_id);
    transpose_all<<<dim3(16, 16, 27), 256, 0, stream>>>(
        wg, wu, wdn, swg, swu, swd, wgT, wuT, wdnT, swgT, swuT, swdT);

    gateup_all<<<dim3(T_TOK / 128, IDIM / 64, NEXP + 1), 256, 0, stream>>>(
        Xb, wgT, wuT, swgT, swuT, hs, hp, counts, pair_id);

    down_routed<<<dim3(T_TOK / 128, HDIM / 128, NEXP), 256, 0, stream>>>(
        hp, wdnT, out, y1, wpair, counts, pair_id);

    down_shared_combine<<<dim3(T_TOK / 128, HDIM / 128, 1), 256, 0, stream>>>(
        hs, swdT, y1, out);
}

// Round 6
// 247.270 us; speedup vs baseline: 1.1735x; 1.1400x over previous
//
#include <hip/hip_runtime.h>
#include <math.h>
#include <stdint.h>

#define T_TOK 8192
#define HDIM 1024
#define IDIM 512
#define NEXP 8
#define NGRP 2
#define EPG 4

typedef unsigned short u16;
typedef __attribute__((ext_vector_type(8))) short short8;   // 8 bf16 in 4 VGPRs
typedef __attribute__((ext_vector_type(4))) float f32x4;

// async global->LDS, 16B per lane; LDS dest is wave-uniform base (HW adds lane*16)
#define GLD16(gp, lp) __builtin_amdgcn_global_load_lds(                        \
    (const __attribute__((address_space(1))) unsigned int*)(gp),               \
    (__attribute__((address_space(3))) unsigned int*)(lp), 16, 0, 0)

__device__ __forceinline__ u16 f2bf(float f) {  // RNE float->bf16
    unsigned int u = __float_as_uint(f);
    u += 0x7fffu + ((u >> 16) & 1u);
    return (u16)(u >> 16);
}
__device__ __forceinline__ float bf2f(u16 v) {
    return __uint_as_float(((unsigned int)v) << 16);
}

// ---------------- router: one wave per token; no atomics ----------------
__global__ __launch_bounds__(256)
void router_kernel(const float* __restrict__ X,
                   const float* __restrict__ Wr,    // [E,H]
                   const float* __restrict__ bias,  // [E]
                   u16* __restrict__ Xb,            // [T,H] bf16 out
                   float* __restrict__ wpair,       // [2T]
                   int* __restrict__ topk_ids)      // [T] packed i0 | i1<<8
{
    int wave = threadIdx.x >> 6;
    int lane = threadIdx.x & 63;
    int t = blockIdx.x * 4 + wave;
    if (t >= T_TOK) return;

    float acc[NEXP];
#pragma unroll
    for (int e = 0; e < NEXP; ++e) acc[e] = 0.f;

    const float4* X4 = (const float4*)(X + (size_t)t * HDIM);
#pragma unroll
    for (int jj = 0; jj < 4; ++jj) {
        float4 xv = X4[lane + jj * 64];
        ushort4 bv;
        bv.x = f2bf(xv.x); bv.y = f2bf(xv.y); bv.z = f2bf(xv.z); bv.w = f2bf(xv.w);
        *(ushort4*)(Xb + (size_t)t * HDIM + (size_t)(lane + jj * 64) * 4) = bv;
#pragma unroll
        for (int e = 0; e < NEXP; ++e) {
            const float4* W4 = (const float4*)(Wr + (size_t)e * HDIM);
            float4 wv = W4[lane + jj * 64];
            acc[e] += xv.x * wv.x + xv.y * wv.y + xv.z * wv.z + xv.w * wv.w;
        }
    }
#pragma unroll
    for (int e = 0; e < NEXP; ++e) {
#pragma unroll
        for (int off = 32; off >= 1; off >>= 1)
            acc[e] += __shfl_xor(acc[e], off, 64);
    }

    if (lane == 0) {
        float s[NEXP], b[NEXP];
#pragma unroll
        for (int e = 0; e < NEXP; ++e) {
            s[e] = 1.f / (1.f + expf(-acc[e]));
            b[e] = s[e] + bias[e];
        }
        float gs[NGRP];
#pragma unroll
        for (int g = 0; g < NGRP; ++g) {
            float m1 = -1e30f, m2 = -1e30f;
#pragma unroll
            for (int j = 0; j < EPG; ++j) {
                float v = b[g * EPG + j];
                if (v > m1) { m2 = m1; m1 = v; }
                else if (v > m2) { m2 = v; }
            }
            gs[g] = m1 + m2;
        }
        int bg = (gs[1] > gs[0]) ? 1 : 0;
        float masked[NEXP];
#pragma unroll
        for (int e = 0; e < NEXP; ++e)
            masked[e] = ((e >> 2) == bg) ? b[e] : 0.0f;
        int i0 = 0; float v0 = masked[0];
#pragma unroll
        for (int e = 1; e < NEXP; ++e)
            if (masked[e] > v0) { v0 = masked[e]; i0 = e; }
        int i1 = -1; float v1 = -1e30f;
#pragma unroll
        for (int e = 0; e < NEXP; ++e) {
            if (e == i0) continue;
            if (masked[e] > v1) { v1 = masked[e]; i1 = e; }
        }
        float w0 = s[i0], w1 = s[i1];
        float inv = 1.f / (w0 + w1 + 1e-20f);
        w0 *= inv; w1 *= inv;
        wpair[t * 2 + 0] = w0;
        wpair[t * 2 + 1] = w1;
        topk_ids[t] = i0 | (i1 << 8);
    }
}

// ---------------- build per-expert pair lists (deterministic compaction) ----------------
__global__ __launch_bounds__(256)
void build_lists(const int* __restrict__ topk_ids,
                 int* __restrict__ counts,
                 int* __restrict__ pair_id)
{
    const int e = blockIdx.x;
    const int tid = threadIdx.x;
    const int lane = tid & 63;
    const int wid = tid >> 6;
    __shared__ int wsum[4];
    __shared__ int rb;
    if (tid == 0) rb = 0;
    __syncthreads();

    int* dst = pair_id + e * T_TOK;
    for (int c0 = 0; c0 < T_TOK; c0 += 256) {
        int t = c0 + tid;
        int ids = topk_ids[t];
        bool m0 = (ids & 0xff) == e;
        bool m1 = ((ids >> 8) & 0xff) == e;
        unsigned long long b0 = __ballot(m0);
        unsigned long long b1 = __ballot(m1);
        int n0 = __popcll(b0);
        int n1 = __popcll(b1);
        if (lane == 0) wsum[wid] = n0 + n1;
        __syncthreads();
        int pre = 0, tot = 0;
#pragma unroll
        for (int w = 0; w < 4; ++w) {
            int v = wsum[w];
            if (w < wid) pre += v;
            tot += v;
        }
        int mybase = rb + pre;
        unsigned long long ltmask = (lane == 63) ? ~0ull >> 1 : ((1ull << lane) - 1);
        if (m0) dst[mybase + __popcll(b0 & ltmask)] = t * 2;
        if (m1) dst[mybase + n0 + __popcll(b1 & ltmask)] = t * 2 + 1;
        __syncthreads();
        if (tid == 0) rb += tot;
    }
    __syncthreads();
    if (tid == 0) counts[e] = rb;
}

// ---------------- merged transpose + fp32->bf16 convert ----------------
__global__ __launch_bounds__(256)
void transpose_all(const float* __restrict__ wg,  const float* __restrict__ wu,
                   const float* __restrict__ wdn, const float* __restrict__ swg,
                   const float* __restrict__ swu, const float* __restrict__ swd,
                   u16* __restrict__ wgT, u16* __restrict__ wuT, u16* __restrict__ wdnT,
                   u16* __restrict__ swgT, u16* __restrict__ swuT, u16* __restrict__ swdT)
{
    const int z = blockIdx.z;
    const float* src; u16* dst; int R, C;
    const size_t EW = (size_t)HDIM * IDIM;
    if (z < 8)       { src = wg  + (size_t)z * EW;        dst = wgT  + (size_t)z * EW;        R = HDIM; C = IDIM; }
    else if (z < 16) { src = wu  + (size_t)(z - 8) * EW;  dst = wuT  + (size_t)(z - 8) * EW;  R = HDIM; C = IDIM; }
    else if (z < 24) { src = wdn + (size_t)(z - 16) * EW; dst = wdnT + (size_t)(z - 16) * EW; R = IDIM; C = HDIM; }
    else if (z == 24){ src = swg; dst = swgT; R = HDIM; C = IDIM; }
    else if (z == 25){ src = swu; dst = swuT; R = HDIM; C = IDIM; }
    else             { src = swd; dst = swdT; R = IDIM; C = HDIM; }
    int r0 = blockIdx.x * 64, c0 = blockIdx.y * 64;
    if (r0 >= R || c0 >= C) return;

    __shared__ float tile[64][65];
    int t = threadIdx.x;
    int row = t >> 2;
#pragma unroll
    for (int j = 0; j < 4; ++j) {
        int c = ((t & 3) + j * 4) * 4;
        *(float4*)&tile[row][c] = *(const float4*)(src + (size_t)(r0 + row) * C + c0 + c);
    }
    __syncthreads();
    int c = t >> 2;
    int rchunk = (t & 3) * 16;
    __attribute__((aligned(16))) u16 pack[16];
#pragma unroll
    for (int i = 0; i < 16; ++i)
        pack[i] = f2bf(tile[rchunk + i][c]);
    uint4* d4 = (uint4*)(dst + (size_t)(c0 + c) * R + r0 + rchunk);
    d4[0] = *(uint4*)&pack[0];
    d4[1] = *(uint4*)&pack[8];
}

// ---------------- merged gate/up MFMA GEMM + SiLU -> h (bf16) ----------------
// m97 structure: BK=64, 32KB LDS single-buffered, XOR-swizzled (0 conflicts), 2 barriers/K-step.
// z=0: shared (Xb -> hs). z=1..8: expert z-1 (gathered Xb -> hp by pair id).
__global__ __launch_bounds__(256)
void gateup_all(const u16* __restrict__ Xb,
                const u16* __restrict__ WgT, const u16* __restrict__ WuT,     // [E,I,H]
                const u16* __restrict__ sWgT, const u16* __restrict__ sWuT,   // [I,H]
                u16* __restrict__ hs,   // [T,I]
                u16* __restrict__ hp,   // [2T,I]
                const int* __restrict__ counts,
                const int* __restrict__ pair_id)
{
    const int z = blockIdx.z;
    const bool SH = (z == 0);
    const int e = z - 1;
    const int nrows = SH ? T_TOK : counts[e];
    const int bm0 = blockIdx.x * 128;
    if (bm0 >= nrows) return;
    const int bn0 = blockIdx.y * 64;
    const u16* wgT = SH ? sWgT : WgT + (size_t)e * HDIM * IDIM;
    const u16* wuT = SH ? sWuT : WuT + (size_t)e * HDIM * IDIM;
    const int* plist = SH ? nullptr : (pair_id + e * T_TOK);
    u16* hout = SH ? hs : hp;

    __shared__ __attribute__((aligned(16))) short As[128 * 64];  // 16 KB
    __shared__ __attribute__((aligned(16))) short Bg[64 * 64];   // 8 KB
    __shared__ __attribute__((aligned(16))) short Bu[64 * 64];   // 8 KB

    const int tid = threadIdx.x;
    const int lane = tid & 63;
    const int wid = tid >> 6;

    // staging: pre-swizzled global source, linear LDS dest (both-sides swizzle, m201 pattern)
    const char* aptr[4];
#pragma unroll
    for (int i = 0; i < 4; ++i) {
        int r = (wid * 4 + i) * 8 + (lane >> 3);
        int row = bm0 + r;
        int srow;
        if (SH) srow = row;
        else    srow = (row < nrows) ? (plist[row] >> 1) : 0;
        int cslot = ((lane & 7) ^ (r & 7)) * 8;
        aptr[i] = (const char*)(Xb + (size_t)srow * HDIM + cslot);
    }
    const char* bgptr[2]; const char* buptr[2];
#pragma unroll
    for (int i = 0; i < 2; ++i) {
        int r = (wid * 2 + i) * 8 + (lane >> 3);
        int nn = bn0 + r;
        int cslot = ((lane & 7) ^ (r & 7)) * 8;
        bgptr[i] = (const char*)(wgT + (size_t)nn * HDIM + cslot);
        buptr[i] = (const char*)(wuT + (size_t)nn * HDIM + cslot);
    }

    const int wm = wid >> 1, wn = wid & 1;
    const int m0 = wm * 64, n0 = wn * 32;
    const int lr = lane & 15, lg = lane >> 4;

    f32x4 accg[4][2] = {};
    f32x4 accu[4][2] = {};

    for (int k0 = 0; k0 < HDIM; k0 += 64) {
#pragma unroll
        for (int i = 0; i < 4; ++i) {
            GLD16(aptr[i], (char*)As + (wid * 4 + i) * 1024);
            aptr[i] += 128;
        }
#pragma unroll
        for (int i = 0; i < 2; ++i) {
            GLD16(bgptr[i], (char*)Bg + (wid * 2 + i) * 1024);
            GLD16(buptr[i], (char*)Bu + (wid * 2 + i) * 1024);
            bgptr[i] += 128; buptr[i] += 128;
        }
        __syncthreads();   // drains vmcnt -> LDS tiles ready
#pragma unroll
        for (int kk = 0; kk < 2; ++kk) {
            short8 af[4], bgf[2], buf_[2];
#pragma unroll
            for (int mf = 0; mf < 4; ++mf) {
                int row = m0 + mf * 16 + lr;
                int slot = (kk * 4 + lg) ^ (row & 7);
                af[mf] = *(const short8*)((const char*)As + row * 128 + slot * 16);
            }
#pragma unroll
            for (int nf = 0; nf < 2; ++nf) {
                int row = n0 + nf * 16 + lr;
                int slot = (kk * 4 + lg) ^ (row & 7);
                bgf[nf]  = *(const short8*)((const char*)Bg + row * 128 + slot * 16);
                buf_[nf] = *(const short8*)((const char*)Bu + row * 128 + slot * 16);
            }
#pragma unroll
            for (int mf = 0; mf < 4; ++mf)
#pragma unroll
                for (int nf = 0; nf < 2; ++nf) {
                    accg[mf][nf] = __builtin_amdgcn_mfma_f32_16x16x32_bf16(af[mf], bgf[nf],  accg[mf][nf], 0, 0, 0);
                    accu[mf][nf] = __builtin_amdgcn_mfma_f32_16x16x32_bf16(af[mf], buf_[nf], accu[mf][nf], 0, 0, 0);
                }
        }
        __syncthreads();   // all reads done before next stage overwrites
    }

    // epilogue: C/D layout col=lane&15, row=4*(lane>>4)+reg
#pragma unroll
    for (int mf = 0; mf < 4; ++mf) {
#pragma unroll
        for (int j = 0; j < 4; ++j) {
            int row = bm0 + m0 + mf * 16 + lg * 4 + j;
            if (row >= nrows) continue;
            int outrow = SH ? row : plist[row];
            u16* dst = hout + (size_t)outrow * IDIM + bn0 + n0 + lr;
#pragma unroll
            for (int nf = 0; nf < 2; ++nf) {
                float g = accg[mf][nf][j], u = accu[mf][nf][j];
                float sg = g / (1.f + __expf(-g));
                dst[nf * 16] = f2bf(sg * u);
            }
        }
    }
}

// ---------------- routed down: slot0 -> out (fp32, exclusive rows), slot1 -> y1 (bf16) ----------------
__global__ __launch_bounds__(256)
void down_routed(const u16* __restrict__ Hp,      // [2T,I]
                 const u16* __restrict__ WdT,     // [E,H,I]
                 float* __restrict__ out,         // [T,H]
                 u16* __restrict__ y1,            // [T,H]
                 const float* __restrict__ wpair,
                 const int* __restrict__ counts,
                 const int* __restrict__ pair_id)
{
    const int e = blockIdx.z;
    const int nrows = counts[e];
    const int bm0 = blockIdx.x * 128;
    if (bm0 >= nrows) return;
    const int bn0 = blockIdx.y * 128;
    const u16* wdT = WdT + (size_t)e * HDIM * IDIM;
    const int* plist = pair_id + e * T_TOK;

    __shared__ __attribute__((aligned(16))) short As[128 * 64];  // 16 KB
    __shared__ __attribute__((aligned(16))) short Bs[128 * 64];  // 16 KB

    const int tid = threadIdx.x;
    const int lane = tid & 63;
    const int wid = tid >> 6;

    const char* aptr[4];
#pragma unroll
    for (int i = 0; i < 4; ++i) {
        int r = (wid * 4 + i) * 8 + (lane >> 3);
        int row = bm0 + r;
        int srow = (row < nrows) ? plist[row] : 0;
        int cslot = ((lane & 7) ^ (r & 7)) * 8;
        aptr[i] = (const char*)(Hp + (size_t)srow * IDIM + cslot);
    }
    const char* bptr[4];
#pragma unroll
    for (int i = 0; i < 4; ++i) {
        int r = (wid * 4 + i) * 8 + (lane >> 3);
        int cslot = ((lane & 7) ^ (r & 7)) * 8;
        bptr[i] = (const char*)(wdT + (size_t)(bn0 + r) * IDIM + cslot);
    }

    const int wm = wid >> 1, wn = wid & 1;
    const int m0 = wm * 64, n0 = wn * 64;
    const int lr = lane & 15, lg = lane >> 4;

    f32x4 acc[4][4] = {};

    for (int k0 = 0; k0 < IDIM; k0 += 64) {
#pragma unroll
        for (int i = 0; i < 4; ++i) {
            GLD16(aptr[i], (char*)As + (wid * 4 + i) * 1024);
            GLD16(bptr[i], (char*)Bs + (wid * 4 + i) * 1024);
            aptr[i] += 128; bptr[i] += 128;
        }
        __syncthreads();
#pragma unroll
        for (int kk = 0; kk < 2; ++kk) {
            short8 af[4], bf[4];
#pragma unroll
            for (int mf = 0; mf < 4; ++mf) {
                int row = m0 + mf * 16 + lr;
                int slot = (kk * 4 + lg) ^ (row & 7);
                af[mf] = *(const short8*)((const char*)As + row * 128 + slot * 16);
            }
#pragma unroll
            for (int nf = 0; nf < 4; ++nf) {
                int row = n0 + nf * 16 + lr;
                int slot = (kk * 4 + lg) ^ (row & 7);
                bf[nf] = *(const short8*)((const char*)Bs + row * 128 + slot * 16);
            }
#pragma unroll
            for (int mf = 0; mf < 4; ++mf)
#pragma unroll
                for (int nf = 0; nf < 4; ++nf)
                    acc[mf][nf] = __builtin_amdgcn_mfma_f32_16x16x32_bf16(af[mf], bf[nf], acc[mf][nf], 0, 0, 0);
        }
        __syncthreads();
    }

#pragma unroll
    for (int mf = 0; mf < 4; ++mf) {
#pragma unroll
        for (int j = 0; j < 4; ++j) {
            int row = bm0 + m0 + mf * 16 + lg * 4 + j;
            if (row >= nrows) continue;
            int p = plist[row];
            int t = p >> 1;
            float w = wpair[p];
            if ((p & 1) == 0) {
                float* dst = out + (size_t)t * HDIM + bn0 + n0 + lr;
#pragma unroll
                for (int nf = 0; nf < 4; ++nf)
                    dst[nf * 16] = acc[mf][nf][j] * w;
            } else {
                u16* dst = y1 + (size_t)t * HDIM + bn0 + n0 + lr;
#pragma unroll
                for (int nf = 0; nf < 4; ++nf)
                    dst[nf * 16] = f2bf(acc[mf][nf][j] * w);
            }
        }
    }
}

// ---------------- shared down + combine: out = out(slot0) + y1(slot1) + hs@swd ----------------
__global__ __launch_bounds__(256)
void down_shared_combine(const u16* __restrict__ Hs,   // [T,I]
                         const u16* __restrict__ swdT, // [H,I]
                         const u16* __restrict__ y1,   // [T,H]
                         float* __restrict__ out)      // [T,H]
{
    const int bm0 = blockIdx.x * 128;
    const int bn0 = blockIdx.y * 128;

    __shared__ __attribute__((aligned(16))) short As[128 * 64];
    __shared__ __attribute__((aligned(16))) short Bs[128 * 64];

    const int tid = threadIdx.x;
    const int lane = tid & 63;
    const int wid = tid >> 6;

    const char* aptr[4];
#pragma unroll
    for (int i = 0; i < 4; ++i) {
        int r = (wid * 4 + i) * 8 + (lane >> 3);
        int cslot = ((lane & 7) ^ (r & 7)) * 8;
        aptr[i] = (const char*)(Hs + (size_t)(bm0 + r) * IDIM + cslot);
    }
    const char* bptr[4];
#pragma unroll
    for (int i = 0; i < 4; ++i) {
        int r = (wid * 4 + i) * 8 + (lane >> 3);
        int cslot = ((lane & 7) ^ (r & 7)) * 8;
        bptr[i] = (const char*)(swdT + (size_t)(bn0 + r) * IDIM + cslot);
    }

    const int wm = wid >> 1, wn = wid & 1;
    const int m0 = wm * 64, n0 = wn * 64;
    const int lr = lane & 15, lg = lane >> 4;

    f32x4 acc[4][4] = {};

    for (int k0 = 0; k0 < IDIM; k0 += 64) {
#pragma unroll
        for (int i = 0; i < 4; ++i) {
            GLD16(aptr[i], (char*)As + (wid * 4 + i) * 1024);
            GLD16(bptr[i], (char*)Bs + (wid * 4 + i) * 1024);
            aptr[i] += 128; bptr[i] += 128;
        }
        __syncthreads();
#pragma unroll
        for (int kk = 0; kk < 2; ++kk) {
            short8 af[4], bf[4];
#pragma unroll
            for (int mf = 0; mf < 4; ++mf) {
                int row = m0 + mf * 16 + lr;
                int slot = (kk * 4 + lg) ^ (row & 7);
                af[mf] = *(const short8*)((const char*)As + row * 128 + slot * 16);
            }
#pragma unroll
            for (int nf = 0; nf < 4; ++nf) {
                int row = n0 + nf * 16 + lr;
                int slot = (kk * 4 + lg) ^ (row & 7);
                bf[nf] = *(const short8*)((const char*)Bs + row * 128 + slot * 16);
            }
#pragma unroll
            for (int mf = 0; mf < 4; ++mf)
#pragma unroll
                for (int nf = 0; nf < 4; ++nf)
                    acc[mf][nf] = __builtin_amdgcn_mfma_f32_16x16x32_bf16(af[mf], bf[nf], acc[mf][nf], 0, 0, 0);
        }
        __syncthreads();
    }

#pragma unroll
    for (int mf = 0; mf < 4; ++mf) {
#pragma unroll
        for (int j = 0; j < 4; ++j) {
            int t = bm0 + m0 + mf * 16 + lg * 4 + j;
            float* dst = out + (size_t)t * HDIM + bn0 + n0 + lr;
            const u16* ysrc = y1 + (size_t)t * HDIM + bn0 + n0 + lr;
#pragma unroll
            for (int nf = 0; nf < 4; ++nf) {
                float prev = dst[nf * 16];                  // slot0 contribution
                float yv = bf2f(ysrc[nf * 16]);             // slot1 contribution
                dst[nf * 16] = prev + yv + acc[mf][nf][j];
            }
        }
    }
}

extern "C" void kernel_launch(void* const* d_in, const int* in_sizes, int n_in,
                              void* d_out, int out_size, void* d_ws, size_t ws_size,
                              hipStream_t stream) {
    const float* X    = (const float*)d_in[0];
    const float* Wr   = (const float*)d_in[1];
    const float* bias = (const float*)d_in[2];
    const float* wg   = (const float*)d_in[3];
    const float* wu   = (const float*)d_in[4];
    const float* wdn  = (const float*)d_in[5];
    const float* swg  = (const float*)d_in[6];
    const float* swu  = (const float*)d_in[7];
    const float* swd  = (const float*)d_in[8];
    float* out = (float*)d_out;
    (void)in_sizes; (void)n_in; (void)out_size; (void)ws_size;

    char* ws = (char*)d_ws;
    const size_t MB = 1048576;
    int*   counts   = (int*)ws;                          // 32 B
    float* wpair    = (float*)(ws + 4096);               // 64 KB
    int*   pair_id  = (int*)(ws + 4096 + 65536);         // 256 KB
    int*   topk_ids = (int*)(ws + 524288);               // 32 KB
    u16* Xb   = (u16*)(ws + 1 * MB);                     // 16 MB [T,H]; reused as y1 after gateup
    u16* wgT  = (u16*)(ws + 17 * MB);                    // 8 MB [E,I,H]
    u16* wuT  = (u16*)(ws + 25 * MB);                    // 8 MB
    u16* wdnT = (u16*)(ws + 33 * MB);                    // 8 MB [E,H,I]
    u16* swgT = (u16*)(ws + 41 * MB);                    // 1 MB [I,H]
    u16* swuT = (u16*)(ws + 42 * MB);                    // 1 MB
    u16* swdT = (u16*)(ws + 43 * MB);                    // 1 MB [H,I]
    u16* hs   = (u16*)(ws + 44 * MB);                    // 8 MB [T,I]
    u16* hp   = (u16*)(ws + 52 * MB);                    // 16 MB [2T,I]
    u16* y1   = Xb;                                      // alias: Xb dead after gateup_all

    router_kernel<<<T_TOK / 4, 256, 0, stream>>>(X, Wr, bias, Xb, wpair, topk_ids);
    build_lists<<<NEXP, 256, 0, stream>>>(topk_ids, counts, pair_id);
    transpose_all<<<dim3(16, 16, 27), 256, 0, stream>>>(
        wg, wu, wdn, swg, swu, swd, wgT, wuT, wdnT, swgT, swuT, swdT);

    gateup_all<<<dim3(T_TOK / 128, IDIM / 64, NEXP + 1), 256, 0, stream>>>(
        Xb, wgT, wuT, swgT, swuT, hs, hp, counts, pair_id);

    down_routed<<<dim3(T_TOK / 128, HDIM / 128, NEXP), 256, 0, stream>>>(
        hp, wdnT, out, y1, wpair, counts, pair_id);

    down_shared_combine<<<dim3(T_TOK / 128, HDIM / 128, 1), 256, 0, stream>>>(
        hs, swdT, y1, out);
}